// Round 26
// baseline (56.723 us; speedup 1.0000x reference)
//
#include <hip/hip_runtime.h>

// Problem constants (from reference setup_inputs)
#define BZ 4
#define H 192
#define W 640
#define PIX (H * W)            // 122880 pixels per batch
#define MAXINS 200
#define CAND 16
#define CE 36                  // ch*cw
#define CE4 9                  // float4 groups per pixel
#define BATCH_FLOATS (MAXINS * CE)          // 7200 floats per batch
#define BATCH_F4     (BATCH_FLOATS / 4)     // 1800 float4 per batch
#define COMP_FLOATS (BZ * BATCH_FLOATS)     // 28800 floats
#define COMP_BYTES  (COMP_FLOATS * 4)       // 115200 bytes
#define BPB 192                             // blocks per batch
#define NBLK (BZ * BPB)                     // 768 compress blocks
#define STRIPE (PIX / BPB)                  // 640 contiguous pixels per block
#define HALFP 320                           // pixels per LDS half
#define NROW 48                             // padded elem rows (3 x 16)
#define RSTR 328                            // row stride u16: dword stride 164 = 4 mod 32 (conflict-free b128)
#define MT_TILES 13                         // ceil(200/16)
#define PART_BYTES ((size_t)NBLK * BATCH_FLOATS * 4)   // 22.1 MB (fp32)

typedef __attribute__((ext_vector_type(8))) short short8;
typedef __attribute__((ext_vector_type(4))) float f32x4;

// bf16 RNE pack
__device__ __forceinline__ unsigned short f2bf(float f) {
    unsigned u = __float_as_uint(f);
    unsigned r = (u + 0x7FFFu + ((u >> 16) & 1u)) >> 16;
    return (unsigned short)r;
}

// ============ compress: MFMA one-hot segment-sum =========================
// comp[m][e] = sum_p onehot(mloc[p]==m) * compsrc[p][e] as bf16 MFMA matmul.
// A generated in registers from mloc bytes; B = transposed bf16 stripe in
// LDS (coalesced streaming read of compsrc, no random gather at all).
// r25 post-mortem: random-gather family converged at ~1.5TB/s effective;
// this removes the gather entirely.

__global__ __launch_bounds__(256) void compress_mfma_kernel(
        const int* __restrict__ inst,
        const float4* __restrict__ compsrc,
        float* __restrict__ partials) {
    __shared__ alignas(16) unsigned short bsrcT[NROW * RSTR];  // 31.5 KB
    __shared__ alignas(8)  unsigned char  mloc[STRIPE];

    const int b    = blockIdx.x / BPB;
    const int blk  = blockIdx.x % BPB;
    const int tid  = threadIdx.x;
    const int pix0 = blk * STRIPE;
    const int wave = tid >> 6;
    const int lane = tid & 63;
    const int mcol = lane & 15;              // M-row (A) / N-col (B,C)
    const int kb   = lane >> 4;              // K-block of 8

    // mloc for whole stripe (coalesced u8)
    for (int p = tid; p < STRIPE; p += 256)
        mloc[p] = (unsigned char)inst[b * PIX + pix0 + p];

    // acc[mi][nt]: wave w owns mt = w + 4*mi (mt<13), all 3 nt
    f32x4 acc[4][3];
    #pragma unroll
    for (int mi = 0; mi < 4; ++mi)
        #pragma unroll
        for (int nt = 0; nt < 3; ++nt)
            acc[mi][nt] = (f32x4){0.f, 0.f, 0.f, 0.f};

    const float4* src = compsrc + (size_t)(b * PIX + pix0) * CE4;

    for (int h = 0; h < 2; ++h) {
        __syncthreads();                     // bsrcT free of prev readers
        // ---- stage half-stripe, transposed bf16 (coalesced global read) ----
        for (int t = tid; t < HALFP * CE4; t += 256) {
            const int p  = t / CE4;
            const int e4 = t - p * CE4;
            float4 v = src[(size_t)(h * HALFP + p) * CE4 + e4];
            const int e = e4 * 4;
            bsrcT[(e + 0) * RSTR + p] = f2bf(v.x);
            bsrcT[(e + 1) * RSTR + p] = f2bf(v.y);
            bsrcT[(e + 2) * RSTR + p] = f2bf(v.z);
            bsrcT[(e + 3) * RSTR + p] = f2bf(v.w);
        }
        __syncthreads();
        // ---- compute: 10 K-steps of 32 pixels ----
        for (int kt = 0; kt < HALFP / 32; ++kt) {
            const unsigned long long bytes8 =
                *(const unsigned long long*)&mloc[h * HALFP + kt * 32 + kb * 8];
            short8 bf[3];
            #pragma unroll
            for (int nt = 0; nt < 3; ++nt) {
                const int n = nt * 16 + mcol;
                bf[nt] = *(const short8*)&bsrcT[n * RSTR + kt * 32 + kb * 8];
            }
            int byt[8];
            #pragma unroll
            for (int j = 0; j < 8; ++j)
                byt[j] = (int)((bytes8 >> (8 * j)) & 0xFFu);
            #pragma unroll
            for (int mi = 0; mi < 4; ++mi) {
                const int mt = wave + mi * 4;
                if (mt < MT_TILES) {
                    const int target = mt * 16 + mcol;
                    short8 af;
                    #pragma unroll
                    for (int j = 0; j < 8; ++j)
                        af[j] = (byt[j] == target) ? (short)0x3F80 : (short)0;
                    #pragma unroll
                    for (int nt = 0; nt < 3; ++nt)
                        acc[mi][nt] = __builtin_amdgcn_mfma_f32_16x16x32_bf16(
                            af, bf[nt], acc[mi][nt], 0, 0, 0);
                }
            }
        }
    }

    // ---- store C -> partials (fp32, every (m<200,e<36) exactly once) ----
    float* pout = partials + (size_t)blockIdx.x * BATCH_FLOATS;
    const int row0 = (lane >> 4) * 4;        // C: col=lane&15, row=(lane>>4)*4+r
    #pragma unroll
    for (int mi = 0; mi < 4; ++mi) {
        const int mt = wave + mi * 4;
        if (mt < MT_TILES) {
            #pragma unroll
            for (int nt = 0; nt < 3; ++nt) {
                const int e = nt * 16 + mcol;
                #pragma unroll
                for (int r = 0; r < 4; ++r) {
                    const int m = mt * 16 + row0 + r;
                    if (m < MAXINS && e < CE)
                        pout[m * CE + e] = acc[mi][nt][r];
                }
            }
        }
    }
}

// ============ K2: reduce partials + sel gather ===========================

__global__ void reduce_priv_kernel(const float4* __restrict__ partials,
                                   const int* __restrict__ batchidx,
                                   const float4* __restrict__ selsrc,
                                   float4* __restrict__ comp) {
    const int t = blockIdx.x * blockDim.x + threadIdx.x;   // over 7200 float4
    if (t >= COMP_FLOATS / 4) return;
    const int e4 = t % CE4;
    const int bm = t / CE4;
    const int b  = t / BATCH_F4;
    const int j  = t - b * BATCH_F4;
    const int c  = batchidx[bm];
    float4 acc = selsrc[((size_t)bm * CAND + c) * CE4 + e4];
    const float4* p = partials + (size_t)b * BPB * BATCH_F4 + j;
    #pragma unroll 8
    for (int s = 0; s < BPB; ++s) {
        float4 v = p[(size_t)s * BATCH_F4];
        acc.x += v.x; acc.y += v.y; acc.z += v.z; acc.w += v.w;
    }
    comp[t] = acc;
}

// ============ fallback (tiny ws): direct atomics =========================

__global__ void init_sel_kernel(const int* __restrict__ batchidx,
                                const float4* __restrict__ selsrc,
                                float4* __restrict__ comp) {
    unsigned t = blockIdx.x * blockDim.x + threadIdx.x;
    if (t >= BZ * MAXINS * CE4) return;
    unsigned e4 = t % CE4;
    unsigned bm = t / CE4;
    int c = batchidx[bm];
    comp[bm * CE4 + e4] = selsrc[(bm * CAND + (unsigned)c) * CE4 + e4];
}

__global__ void compress_direct_kernel(const int* __restrict__ inst,
                                       const float4* __restrict__ compsrc,
                                       float* __restrict__ comp) {
    const unsigned total = BZ * PIX * CE4;
    for (unsigned t = blockIdx.x * blockDim.x + threadIdx.x; t < total;
         t += gridDim.x * blockDim.x) {
        unsigned e4 = t % CE4;
        unsigned pix = t / CE4;
        unsigned b = pix / PIX;
        int m = inst[pix];
        float4 v = compsrc[t];
        float* dst = comp + ((unsigned)(b * MAXINS + m)) * CE + e4 * 4;
        atomicAdd(dst + 0, v.x);
        atomicAdd(dst + 1, v.y);
        atomicAdd(dst + 2, v.z);
        atomicAdd(dst + 3, v.w);
    }
}

// ============ K3: inflate ================================================

__global__ void inflate_kernel(const int* __restrict__ inst,
                               const float4* __restrict__ comp,
                               float4* __restrict__ out) {
    const unsigned total = BZ * PIX * CE4;
    for (unsigned t = blockIdx.x * blockDim.x + threadIdx.x; t < total;
         t += gridDim.x * blockDim.x) {
        unsigned e4 = t % CE4;
        unsigned pix = t / CE4;
        unsigned b = pix / PIX;
        int m = inst[pix];
        out[t] = comp[((unsigned)(b * MAXINS + m)) * CE4 + e4];  // L2-hot gather
    }
}

extern "C" void kernel_launch(void* const* d_in, const int* in_sizes, int n_in,
                              void* d_out, int out_size, void* d_ws, size_t ws_size,
                              hipStream_t stream) {
    const int*    inst     = (const int*)d_in[0];      // (BZ,1,H,W) int32
    const float*  compsrc  = (const float*)d_in[1];    // (BZ,H,W,6,6) f32
    const int*    batchidx = (const int*)d_in[2];      // (BZ,MAXINS) int32
    const float*  selsrc   = (const float*)d_in[3];    // (BZ,MAXINS,CAND,6,6) f32
    float*        out      = (float*)d_out;            // (BZ,H,W,6,6) f32
    float*        comp     = (float*)d_ws;             // 115.2 KB @ ws[0]

    if (ws_size >= (size_t)COMP_BYTES + PART_BYTES) {
        // --- main path: MFMA one-hot compress ---
        float* partials = (float*)(comp + COMP_FLOATS);
        compress_mfma_kernel<<<NBLK, 256, 0, stream>>>(inst, (const float4*)compsrc,
                                                       partials);
        reduce_priv_kernel<<<(COMP_FLOATS / 4 + 255) / 256, 256, 0, stream>>>(
            (const float4*)partials, batchidx, (const float4*)selsrc, (float4*)comp);
    } else {
        // --- fallback: direct atomics into comp ---
        const int total = BZ * MAXINS * CE4;
        init_sel_kernel<<<(total + 255) / 256, 256, 0, stream>>>(
            batchidx, (const float4*)selsrc, (float4*)comp);
        compress_direct_kernel<<<2048, 256, 0, stream>>>(inst, (const float4*)compsrc,
                                                         comp);
    }

    // K3: inflate comp back to per-pixel output
    inflate_kernel<<<2048, 256, 0, stream>>>(inst, (const float4*)comp, (float4*)out);
}

// Round 30
// 48.152 us; speedup vs baseline: 1.1780x; 1.1780x over previous
//
#include <hip/hip_runtime.h>

// Problem constants (from reference setup_inputs)
#define BZ 4
#define H 192
#define W 640
#define PIX (H * W)            // 122880 pixels per batch
#define MAXINS 200
#define CAND 16
#define CE 36                  // ch*cw
#define CE4 9                  // float4 groups per pixel
#define BATCH_FLOATS (MAXINS * CE)          // 7200 floats per batch
#define BATCH_F4     (BATCH_FLOATS / 4)     // 1800 float4 per batch
#define COMP_FLOATS (BZ * BATCH_FLOATS)     // 28800 floats
#define COMP_BYTES  (COMP_FLOATS * 4)       // 115200 bytes
#define BPB 192                             // blocks per batch
#define NBLK (BZ * BPB)                     // 768 compress blocks
#define STRIPE (PIX / BPB)                  // 640 contiguous pixels per block
#define TPB 512                             // threads per block
#define ITEMS 4                             // items per thread (item-major)
#define PARTBF_BYTES ((size_t)NBLK * BATCH_F4 * 8)   // 11.1 MB (bf16x4/item)

// bf16 pack/unpack (RNE)
__device__ __forceinline__ unsigned short f2bf(float f) {
    unsigned u = __float_as_uint(f);
    unsigned r = (u + 0x7FFFu + ((u >> 16) & 1u)) >> 16;
    return (unsigned short)r;
}
__device__ __forceinline__ float bf2f(unsigned short h) {
    return __uint_as_float(((unsigned)h) << 16);
}

// ============ compress: r21 counting sort + item-major gather ============
// Nine compress structures measured (r12..r26); this is the best (r21),
// unchanged except partials stored as bf16 (halves the partials traffic;
// r24 validated the numerics, absmax 0.5 << 2.36).

__global__ __launch_bounds__(TPB) void compress_sort_kernel(
        const int* __restrict__ inst,
        const float4* __restrict__ compsrc,
        ushort4* __restrict__ partials) {
    __shared__ unsigned char  mloc[STRIPE];     // per-pixel m (cached)
    __shared__ unsigned short sorted[STRIPE];   // local pixel ids, grouped by m
    __shared__ int cnt[MAXINS];
    __shared__ int off[MAXINS + 1];
    __shared__ int off_run[MAXINS];

    const int b    = blockIdx.x / BPB;
    const int blk  = blockIdx.x % BPB;
    const int tid  = threadIdx.x;
    const int pix0 = blk * STRIPE;

    if (tid < MAXINS) cnt[tid] = 0;
    __syncthreads();                             // barrier 1

    // ---- count pass: 640 int LDS atomics, cache m ----
    for (int p = tid; p < STRIPE; p += TPB) {
        int m = inst[b * PIX + pix0 + p];        // coalesced
        mloc[p] = (unsigned char)m;
        atomicAdd(&cnt[m], 1);                   // ds_add_u32
    }
    __syncthreads();                             // barrier 2

    // ---- single-wave exclusive scan (wave 0, shfl, no barriers) ----
    if (tid < 64) {
        const int lane = tid;
        int run = 0;
        #pragma unroll
        for (int c = 0; c < 4; ++c) {            // 4 chunks of 64 bins
            const int idx = c * 64 + lane;       // 0..255
            int v = (idx < MAXINS) ? cnt[idx] : 0;
            const int own = v;
            #pragma unroll
            for (int s = 1; s < 64; s <<= 1) {   // inclusive wave scan
                int u = __shfl_up(v, s);
                if (lane >= s) v += u;
            }
            const int excl = run + v - own;
            if (idx < MAXINS) { off[idx] = excl; off_run[idx] = excl; }
            run += __shfl(v, 63);                // chunk total
        }
        if (lane == 0) off[MAXINS] = STRIPE;
    }
    __syncthreads();                             // barrier 3

    // ---- scatter local pixel ids into m-sorted order ----
    for (int p = tid; p < STRIPE; p += TPB) {
        int slot = atomicAdd(&off_run[mloc[p]], 1);   // ds_add_rtn_u32
        sorted[slot] = (unsigned short)p;
    }
    __syncthreads();                             // barrier 4

    // ---- phase 2: r12-exact item-major register accumulation ----
    const float4* src = compsrc + (size_t)(b * PIX + pix0) * CE4;
    float4 acc[ITEMS];
    int base_[ITEMS], len_[ITEMS], e4_[ITEMS], idx_[ITEMS];
    int maxlen = 0;
    #pragma unroll
    for (int j = 0; j < ITEMS; ++j) {
        const int item = tid + TPB * j;
        acc[j] = make_float4(0.f, 0.f, 0.f, 0.f);
        if (item < BATCH_F4) {
            const int m  = item / CE4;
            e4_[j]   = item - m * CE4;
            base_[j] = off[m];
            len_[j]  = off[m + 1] - off[m];
            maxlen   = len_[j] > maxlen ? len_[j] : maxlen;
        } else { base_[j] = 0; len_[j] = 0; e4_[j] = 0; }
        idx_[j] = (0 < len_[j]) ? (int)sorted[base_[j]] : 0;
    }
    for (int i = 0; i < maxlen; ++i) {
        float4 v[ITEMS];
        #pragma unroll
        for (int j = 0; j < ITEMS; ++j)
            if (i < len_[j]) v[j] = src[(size_t)idx_[j] * CE4 + e4_[j]];
        #pragma unroll
        for (int j = 0; j < ITEMS; ++j)
            idx_[j] = (i + 1 < len_[j]) ? (int)sorted[base_[j] + i + 1] : 0;
        #pragma unroll
        for (int j = 0; j < ITEMS; ++j)
            if (i < len_[j]) {
                acc[j].x += v[j].x; acc[j].y += v[j].y;
                acc[j].z += v[j].z; acc[j].w += v[j].w;
            }
    }

    // ---- store full partial as bf16 (every byte overwritten) ----
    ushort4* p = partials + (size_t)blockIdx.x * BATCH_F4;
    #pragma unroll
    for (int j = 0; j < ITEMS; ++j) {
        const int item = tid + TPB * j;
        if (item < BATCH_F4) {
            ushort4 w;
            w.x = f2bf(acc[j].x); w.y = f2bf(acc[j].y);
            w.z = f2bf(acc[j].z); w.w = f2bf(acc[j].w);
            p[item] = w;                          // coalesced 8B/lane
        }
    }
}

// ============ K2: reduce bf16 partials + sel gather ======================

__global__ void reduce_priv_kernel(const ushort4* __restrict__ partials,
                                   const int* __restrict__ batchidx,
                                   const float4* __restrict__ selsrc,
                                   float4* __restrict__ comp) {
    const int t = blockIdx.x * blockDim.x + threadIdx.x;   // over 7200 float4
    if (t >= COMP_FLOATS / 4) return;
    const int e4 = t % CE4;
    const int bm = t / CE4;
    const int b  = t / BATCH_F4;
    const int j  = t - b * BATCH_F4;
    const int c  = batchidx[bm];
    float4 acc = selsrc[((size_t)bm * CAND + c) * CE4 + e4];
    const ushort4* p = partials + (size_t)b * BPB * BATCH_F4 + j;
    #pragma unroll 8
    for (int s = 0; s < BPB; ++s) {
        ushort4 w = p[(size_t)s * BATCH_F4];
        acc.x += bf2f(w.x); acc.y += bf2f(w.y);
        acc.z += bf2f(w.z); acc.w += bf2f(w.w);
    }
    comp[t] = acc;
}

// ============ fallback (tiny ws): direct atomics =========================

__global__ void init_sel_kernel(const int* __restrict__ batchidx,
                                const float4* __restrict__ selsrc,
                                float4* __restrict__ comp) {
    unsigned t = blockIdx.x * blockDim.x + threadIdx.x;
    if (t >= BZ * MAXINS * CE4) return;
    unsigned e4 = t % CE4;
    unsigned bm = t / CE4;
    int c = batchidx[bm];
    comp[bm * CE4 + e4] = selsrc[(bm * CAND + (unsigned)c) * CE4 + e4];
}

__global__ void compress_direct_kernel(const int* __restrict__ inst,
                                       const float4* __restrict__ compsrc,
                                       float* __restrict__ comp) {
    const unsigned total = BZ * PIX * CE4;
    for (unsigned t = blockIdx.x * blockDim.x + threadIdx.x; t < total;
         t += gridDim.x * blockDim.x) {
        unsigned e4 = t % CE4;
        unsigned pix = t / CE4;
        unsigned b = pix / PIX;
        int m = inst[pix];
        float4 v = compsrc[t];
        float* dst = comp + ((unsigned)(b * MAXINS + m)) * CE + e4 * 4;
        atomicAdd(dst + 0, v.x);
        atomicAdd(dst + 1, v.y);
        atomicAdd(dst + 2, v.z);
        atomicAdd(dst + 3, v.w);
    }
}

// ============ K3: inflate ================================================

__global__ void inflate_kernel(const int* __restrict__ inst,
                               const float4* __restrict__ comp,
                               float4* __restrict__ out) {
    const unsigned total = BZ * PIX * CE4;
    for (unsigned t = blockIdx.x * blockDim.x + threadIdx.x; t < total;
         t += gridDim.x * blockDim.x) {
        unsigned e4 = t % CE4;
        unsigned pix = t / CE4;
        unsigned b = pix / PIX;
        int m = inst[pix];
        out[t] = comp[((unsigned)(b * MAXINS + m)) * CE4 + e4];  // L2-hot gather
    }
}

extern "C" void kernel_launch(void* const* d_in, const int* in_sizes, int n_in,
                              void* d_out, int out_size, void* d_ws, size_t ws_size,
                              hipStream_t stream) {
    const int*    inst     = (const int*)d_in[0];      // (BZ,1,H,W) int32
    const float*  compsrc  = (const float*)d_in[1];    // (BZ,H,W,6,6) f32
    const int*    batchidx = (const int*)d_in[2];      // (BZ,MAXINS) int32
    const float*  selsrc   = (const float*)d_in[3];    // (BZ,MAXINS,CAND,6,6) f32
    float*        out      = (float*)d_out;            // (BZ,H,W,6,6) f32
    float*        comp     = (float*)d_ws;             // 115.2 KB @ ws[0]

    if (ws_size >= (size_t)COMP_BYTES + PARTBF_BYTES) {
        // --- main path: r21 counting-sort compress, bf16 partials ---
        ushort4* partials = (ushort4*)(comp + COMP_FLOATS);
        compress_sort_kernel<<<NBLK, TPB, 0, stream>>>(inst, (const float4*)compsrc,
                                                       partials);
        reduce_priv_kernel<<<(COMP_FLOATS / 4 + 255) / 256, 256, 0, stream>>>(
            partials, batchidx, (const float4*)selsrc, (float4*)comp);
    } else {
        // --- fallback: direct atomics into comp ---
        const int total = BZ * MAXINS * CE4;
        init_sel_kernel<<<(total + 255) / 256, 256, 0, stream>>>(
            batchidx, (const float4*)selsrc, (float4*)comp);
        compress_direct_kernel<<<2048, 256, 0, stream>>>(inst, (const float4*)compsrc,
                                                         comp);
    }

    // K3: inflate comp back to per-pixel output
    inflate_kernel<<<2048, 256, 0, stream>>>(inst, (const float4*)comp, (float4*)out);
}